// Round 9
// baseline (424.703 us; speedup 1.0000x reference)
//
#include <hip/hip_runtime.h>
#include <hip/hip_bf16.h>

typedef __bf16 bf16_t;
typedef __bf16 bf16x8 __attribute__((ext_vector_type(8)));
typedef float f32x4 __attribute__((ext_vector_type(4)));
typedef unsigned int uint;

#define T_TOK 4096
#define H_DIM 7168
#define QLORA 1536
#define KVLORA 512
#define ROPE_D 64
#define NOPE_D 128
#define NHEAD 16
#define NQKV 2112   /* QLORA + KVLORA + ROPE */
#define NQB  3072   /* NHEAD * 192 */
#define EPS_F 1e-6f

// ---------------- elementwise helpers ----------------

__global__ void cast_f32_bf16(const float* __restrict__ in, bf16_t* __restrict__ out, long n8)
{
    long stride = (long)gridDim.x * blockDim.x;
    for (long i = (long)blockIdx.x * blockDim.x + threadIdx.x; i < n8; i += stride) {
        const float4 a = ((const float4*)in)[i * 2];
        const float4 b = ((const float4*)in)[i * 2 + 1];
        bf16x8 v;
        v[0] = (bf16_t)a.x; v[1] = (bf16_t)a.y; v[2] = (bf16_t)a.z; v[3] = (bf16_t)a.w;
        v[4] = (bf16_t)b.x; v[5] = (bf16_t)b.y; v[6] = (bf16_t)b.z; v[7] = (bf16_t)b.w;
        ((bf16x8*)out)[i] = v;
    }
}

// out[C][R] (bf16) = transpose of in[R][C] (f32)
__global__ __launch_bounds__(256) void transpose_cast(const float* __restrict__ in,
                                                      bf16_t* __restrict__ out, int R, int C)
{
    __shared__ float tile[32][33];
    const int bx = blockIdx.x * 32;   // col block of in
    const int by = blockIdx.y * 32;   // row block of in
    const int tx = threadIdx.x & 31, ty = threadIdx.x >> 5;
    #pragma unroll
    for (int r = ty; r < 32; r += 8)
        tile[r][tx] = in[(long)(by + r) * C + bx + tx];
    __syncthreads();
    #pragma unroll
    for (int r = ty; r < 32; r += 8)
        out[(long)(bx + r) * R + by + tx] = (bf16_t)tile[tx][r];
}

// block reduction safe for repeated use (leading+trailing barriers)
__device__ inline float block_sum_256(float v)
{
    #pragma unroll
    for (int off = 32; off > 0; off >>= 1) v += __shfl_xor(v, off, 64);
    __shared__ float tmp[4];
    __syncthreads();
    if ((threadIdx.x & 63) == 0) tmp[threadIdx.x >> 6] = v;
    __syncthreads();
    return tmp[0] + tmp[1] + tmp[2] + tmp[3];
}

// fused: RMS-norm q-lora -> bf16 q_a;  RMS-norm latent + rope -> k_out/caches
__global__ __launch_bounds__(256) void rmsq_kside_kernel(
    const float* __restrict__ qkv, const float* __restrict__ qkvB,
    const float* __restrict__ q_w, const float* __restrict__ kv_w,
    const float* __restrict__ cos_sin, const int* __restrict__ positions,
    const int* __restrict__ slot_map,
    bf16_t* __restrict__ q_a, float* __restrict__ k_out,
    float* __restrict__ kc_out, float* __restrict__ rc_out)
{
    const int t = blockIdx.x;
    const float* x = qkv + (long)t * NQKV;
    const float* xB = qkvB ? qkvB + (long)t * NQKV : nullptr;

    // ---- q side: 1536 elems, 6/thread ----
    float loc[6];
    float ss = 0.f;
    #pragma unroll
    for (int i = 0; i < 6; i++) {
        int idx = threadIdx.x + 256 * i;
        float v = x[idx];
        if (xB) v += xB[idx];
        loc[i] = v; ss += v * v;
    }
    ss = block_sum_256(ss);
    const float scq = rsqrtf(ss / (float)QLORA + EPS_F);
    #pragma unroll
    for (int i = 0; i < 6; i++) {
        int idx = threadIdx.x + 256 * i;
        q_a[(long)t * QLORA + idx] = (bf16_t)(loc[i] * scq * q_w[idx]);
    }

    // ---- k side: latent 512 + rope 64 ----
    const float* lat = x + QLORA;
    const float* latB = xB ? xB + QLORA : nullptr;
    float v0 = lat[threadIdx.x];
    float v1 = lat[threadIdx.x + 256];
    if (latB) { v0 += latB[threadIdx.x]; v1 += latB[threadIdx.x + 256]; }
    float ssk = v0 * v0 + v1 * v1;
    ssk = block_sum_256(ssk);
    const float sck = rsqrtf(ssk / (float)KVLORA + EPS_F);
    const int slot = slot_map[t];
    const float a0 = v0 * sck * kv_w[threadIdx.x];
    const float a1 = v1 * sck * kv_w[threadIdx.x + 256];
    k_out[(long)t * 576 + threadIdx.x]        = a0;
    k_out[(long)t * 576 + 256 + threadIdx.x]  = a1;
    kc_out[(long)slot * KVLORA + threadIdx.x]       = a0;
    kc_out[(long)slot * KVLORA + 256 + threadIdx.x] = a1;
    if (threadIdx.x < 32) {
        const int j = threadIdx.x;
        const int pos = positions[t];
        const float c = cos_sin[pos * 64 + j];
        const float s = cos_sin[pos * 64 + 32 + j];
        float x1 = lat[KVLORA + 2 * j];
        float x2 = lat[KVLORA + 2 * j + 1];
        if (latB) { x1 += latB[KVLORA + 2 * j]; x2 += latB[KVLORA + 2 * j + 1]; }
        const float o1 = x1 * c - x2 * s;
        const float o2 = x2 * c + x1 * s;
        k_out[(long)t * 576 + 512 + j]      = o1;
        k_out[(long)t * 576 + 512 + 32 + j] = o2;
        rc_out[(long)slot * 64 + j]      = o1;
        rc_out[(long)slot * 64 + 32 + j] = o2;
    }
}

// ------- 256x128-tile 2-phase dbuf bf16 MFMA GEMM, bank-swizzled LDS ---------
// C(MxN f32) = A(MxK bf16) * B^T(NxK bf16); M%256==0, K%64==0; N edge clamped.
// BK=64, 8 waves in 4Mx2N grid, wave tile 64x64 (4x4 acc = 32 MFMA/K-step,
// 16 ds_read_b128 -> 0.5 reads/MFMA). Same sync structure as the verified r5
// kernel: gload_lds staging, next tile staged BEFORE compute, one
// vmcnt(0)+barrier per K-step. Bank swizzle (rule #21, both sides): physical
// col byte c of row r at c ^ ((r&7)<<4); write side pre-swizzles the GLOBAL
// col chunk; read side XORs the frag base; ks=1 = base ^ 64.
#define GBM 256
#define GBN 128
#define GBK 64
#define ABYTES (GBM * GBK * 2)   /* 32 KB per A buffer */
#define BBYTES (GBN * GBK * 2)   /* 16 KB per B buffer */

// common per-K-step compute: 16 swizzled ds_read_b128 + 32 MFMA
#define GEMM_TILE_COMPUTE(aa, bb)                                                            \
    const uint aaX = (aa) ^ 64u;                                                             \
    const uint bbX = (bb) ^ 64u;                                                             \
    bf16x8 aV0, aV1, aV2, aV3, aX0, aX1, aX2, aX3;                                           \
    bf16x8 bV0, bV1, bV2, bV3, bX0, bX1, bX2, bX3;                                           \
    asm volatile("ds_read_b128 %0, %1 offset:0"    : "=v"(aV0) : "v"(aa));                   \
    asm volatile("ds_read_b128 %0, %1 offset:2048" : "=v"(aV1) : "v"(aa));                   \
    asm volatile("ds_read_b128 %0, %1 offset:4096" : "=v"(aV2) : "v"(aa));                   \
    asm volatile("ds_read_b128 %0, %1 offset:6144" : "=v"(aV3) : "v"(aa));                   \
    asm volatile("ds_read_b128 %0, %1 offset:0"    : "=v"(aX0) : "v"(aaX));                  \
    asm volatile("ds_read_b128 %0, %1 offset:2048" : "=v"(aX1) : "v"(aaX));                  \
    asm volatile("ds_read_b128 %0, %1 offset:4096" : "=v"(aX2) : "v"(aaX));                  \
    asm volatile("ds_read_b128 %0, %1 offset:6144" : "=v"(aX3) : "v"(aaX));                  \
    asm volatile("ds_read_b128 %0, %1 offset:0"    : "=v"(bV0) : "v"(bb));                   \
    asm volatile("ds_read_b128 %0, %1 offset:2048" : "=v"(bV1) : "v"(bb));                   \
    asm volatile("ds_read_b128 %0, %1 offset:4096" : "=v"(bV2) : "v"(bb));                   \
    asm volatile("ds_read_b128 %0, %1 offset:6144" : "=v"(bV3) : "v"(bb));                   \
    asm volatile("ds_read_b128 %0, %1 offset:0"    : "=v"(bX0) : "v"(bbX));                  \
    asm volatile("ds_read_b128 %0, %1 offset:2048" : "=v"(bX1) : "v"(bbX));                  \
    asm volatile("ds_read_b128 %0, %1 offset:4096" : "=v"(bX2) : "v"(bbX));                  \
    asm volatile("ds_read_b128 %0, %1 offset:6144" : "=v"(bX3) : "v"(bbX));                  \
    asm volatile("s_waitcnt lgkmcnt(0)" ::: "memory");                                       \
    __builtin_amdgcn_sched_barrier(0);                                                       \
    acc[0][0] = __builtin_amdgcn_mfma_f32_16x16x32_bf16(aV0, bV0, acc[0][0], 0, 0, 0);       \
    acc[0][1] = __builtin_amdgcn_mfma_f32_16x16x32_bf16(aV0, bV1, acc[0][1], 0, 0, 0);       \
    acc[0][2] = __builtin_amdgcn_mfma_f32_16x16x32_bf16(aV0, bV2, acc[0][2], 0, 0, 0);       \
    acc[0][3] = __builtin_amdgcn_mfma_f32_16x16x32_bf16(aV0, bV3, acc[0][3], 0, 0, 0);       \
    acc[1][0] = __builtin_amdgcn_mfma_f32_16x16x32_bf16(aV1, bV0, acc[1][0], 0, 0, 0);       \
    acc[1][1] = __builtin_amdgcn_mfma_f32_16x16x32_bf16(aV1, bV1, acc[1][1], 0, 0, 0);       \
    acc[1][2] = __builtin_amdgcn_mfma_f32_16x16x32_bf16(aV1, bV2, acc[1][2], 0, 0, 0);       \
    acc[1][3] = __builtin_amdgcn_mfma_f32_16x16x32_bf16(aV1, bV3, acc[1][3], 0, 0, 0);       \
    acc[2][0] = __builtin_amdgcn_mfma_f32_16x16x32_bf16(aV2, bV0, acc[2][0], 0, 0, 0);       \
    acc[2][1] = __builtin_amdgcn_mfma_f32_16x16x32_bf16(aV2, bV1, acc[2][1], 0, 0, 0);       \
    acc[2][2] = __builtin_amdgcn_mfma_f32_16x16x32_bf16(aV2, bV2, acc[2][2], 0, 0, 0);       \
    acc[2][3] = __builtin_amdgcn_mfma_f32_16x16x32_bf16(aV2, bV3, acc[2][3], 0, 0, 0);       \
    acc[3][0] = __builtin_amdgcn_mfma_f32_16x16x32_bf16(aV3, bV0, acc[3][0], 0, 0, 0);       \
    acc[3][1] = __builtin_amdgcn_mfma_f32_16x16x32_bf16(aV3, bV1, acc[3][1], 0, 0, 0);       \
    acc[3][2] = __builtin_amdgcn_mfma_f32_16x16x32_bf16(aV3, bV2, acc[3][2], 0, 0, 0);       \
    acc[3][3] = __builtin_amdgcn_mfma_f32_16x16x32_bf16(aV3, bV3, acc[3][3], 0, 0, 0);       \
    acc[0][0] = __builtin_amdgcn_mfma_f32_16x16x32_bf16(aX0, bX0, acc[0][0], 0, 0, 0);       \
    acc[0][1] = __builtin_amdgcn_mfma_f32_16x16x32_bf16(aX0, bX1, acc[0][1], 0, 0, 0);       \
    acc[0][2] = __builtin_amdgcn_mfma_f32_16x16x32_bf16(aX0, bX2, acc[0][2], 0, 0, 0);       \
    acc[0][3] = __builtin_amdgcn_mfma_f32_16x16x32_bf16(aX0, bX3, acc[0][3], 0, 0, 0);       \
    acc[1][0] = __builtin_amdgcn_mfma_f32_16x16x32_bf16(aX1, bX0, acc[1][0], 0, 0, 0);       \
    acc[1][1] = __builtin_amdgcn_mfma_f32_16x16x32_bf16(aX1, bX1, acc[1][1], 0, 0, 0);       \
    acc[1][2] = __builtin_amdgcn_mfma_f32_16x16x32_bf16(aX1, bX2, acc[1][2], 0, 0, 0);       \
    acc[1][3] = __builtin_amdgcn_mfma_f32_16x16x32_bf16(aX1, bX3, acc[1][3], 0, 0, 0);       \
    acc[2][0] = __builtin_amdgcn_mfma_f32_16x16x32_bf16(aX2, bX0, acc[2][0], 0, 0, 0);       \
    acc[2][1] = __builtin_amdgcn_mfma_f32_16x16x32_bf16(aX2, bX1, acc[2][1], 0, 0, 0);       \
    acc[2][2] = __builtin_amdgcn_mfma_f32_16x16x32_bf16(aX2, bX2, acc[2][2], 0, 0, 0);       \
    acc[2][3] = __builtin_amdgcn_mfma_f32_16x16x32_bf16(aX2, bX3, acc[2][3], 0, 0, 0);       \
    acc[3][0] = __builtin_amdgcn_mfma_f32_16x16x32_bf16(aX3, bX0, acc[3][0], 0, 0, 0);       \
    acc[3][1] = __builtin_amdgcn_mfma_f32_16x16x32_bf16(aX3, bX1, acc[3][1], 0, 0, 0);       \
    acc[3][2] = __builtin_amdgcn_mfma_f32_16x16x32_bf16(aX3, bX2, acc[3][2], 0, 0, 0);       \
    acc[3][3] = __builtin_amdgcn_mfma_f32_16x16x32_bf16(aX3, bX3, acc[3][3], 0, 0, 0);

__global__ __launch_bounds__(512) void gemm_mfma(
    const bf16_t* __restrict__ A, int lda, long sA,
    const bf16_t* __restrict__ Bt, int ldb, long sB,
    float* __restrict__ C, int ldc, long sC,
    int K, int N)
{
    __shared__ bf16_t As[2][GBM * GBK];   // 2 x 32 KB
    __shared__ bf16_t Bs[2][GBN * GBK];   // 2 x 16 KB

    const int nwg = gridDim.x * gridDim.y;
    const int bid = blockIdx.y * gridDim.x + blockIdx.x;
    const int cpx = nwg >> 3;
    const int swz = (bid & 7) * cpx + (bid >> 3);
    const int bx = swz % gridDim.x;
    const int by = swz / gridDim.x;

    const int tid = threadIdx.x;
    const int lane = tid & 63;
    const int w = tid >> 6;            // 0..7
    const int wr = w >> 1, wc = w & 1; // 4Mx2N wave grid; wave tile 64x64
    const int fr = lane & 15;
    const int kg = lane >> 4;

    const long brow = (long)by * GBM;
    const long bcol = (long)bx * GBN;

    const bf16_t* Ab = A + blockIdx.z * sA + brow * lda;
    const bf16_t* Bb = Bt + blockIdx.z * sB;
    float* Cb = C + blockIdx.z * sC + brow * ldc;

    // staging: block-issue = 8 KB = 64 rows x 128B; A needs 4 issues, B 2.
    // wave w covers rows it*64 + w*8 + (lane>>3); global col pre-swizzled.
    const int srow = w * 8 + (lane >> 3);
    const int scol = (((lane & 7) ^ (lane >> 3)) * 8);

    const uint rd_sw = (uint)((kg * 16) ^ ((fr & 7) << 4));
    const uint a_base = (uint)(uintptr_t)(&As[0][0]) + (uint)((wr * 64 + fr) * 128) + rd_sw;
    const uint b_base = (uint)(uintptr_t)(&Bs[0][0]) + (uint)((wc * 64 + fr) * 128) + rd_sw;

    f32x4 acc[4][4] = {};

    const int nt = K / GBK;

    auto stage = [&](int buf, int k0) {
        #pragma unroll
        for (int it = 0; it < 4; it++) {
            const int r = it * 64 + srow;
            __builtin_amdgcn_global_load_lds(
                (const __attribute__((address_space(1))) void*)(Ab + (long)r * lda + k0 + scol),
                (__attribute__((address_space(3))) void*)(&As[buf][(it * 64 + w * 8) * GBK]),
                16, 0, 0);
        }
        #pragma unroll
        for (int it = 0; it < 2; it++) {
            const int r = it * 64 + srow;
            long bn = bcol + r; if (bn >= N) bn = N - 1;   // clamp; masked at store
            __builtin_amdgcn_global_load_lds(
                (const __attribute__((address_space(1))) void*)(Bb + bn * ldb + k0 + scol),
                (__attribute__((address_space(3))) void*)(&Bs[buf][(it * 64 + w * 8) * GBK]),
                16, 0, 0);
        }
    };

    stage(0, 0);
    asm volatile("s_waitcnt vmcnt(0)" ::: "memory");
    __builtin_amdgcn_s_barrier();

    int cur = 0;
    for (int t = 0; t < nt; ++t) {
        if (t + 1 < nt) stage(cur ^ 1, (t + 1) * GBK);

        const uint aa = a_base + (uint)(cur * ABYTES);
        const uint bb = b_base + (uint)(cur * BBYTES);
        { GEMM_TILE_COMPUTE(aa, bb) }

        asm volatile("s_waitcnt vmcnt(0)" ::: "memory");
        __builtin_amdgcn_s_barrier();
        cur ^= 1;
    }

    // C/D layout: col = lane&15, row = (lane>>4)*4 + reg
    #pragma unroll
    for (int i = 0; i < 4; i++) {
        #pragma unroll
        for (int j = 0; j < 4; j++) {
            const int row0 = wr * 64 + i * 16 + kg * 4;
            const long col = bcol + wc * 64 + j * 16 + fr;
            if (col < N) {
                #pragma unroll
                for (int r = 0; r < 4; r++)
                    Cb[(long)(row0 + r) * ldc + col] = acc[i][j][r];
            }
        }
    }
}

// ---------------- GEMM2 with fused split_q epilogue (256x128 geometry) -------
__global__ __launch_bounds__(512) void gemm2_fused(
    const bf16_t* __restrict__ A,   // q_a, lda=QLORA
    const bf16_t* __restrict__ Bt,  // wqbT, ldb=QLORA
    const float* __restrict__ cos_sin,
    const int* __restrict__ positions,
    bf16_t* __restrict__ q_nope,
    float* __restrict__ q_out)
{
    __shared__ bf16_t As[2][GBM * GBK];
    __shared__ bf16_t Bs[2][GBN * GBK];

    const int nwg = gridDim.x * gridDim.y;
    const int bid = blockIdx.y * gridDim.x + blockIdx.x;
    const int cpx = nwg >> 3;
    const int swz = (bid & 7) * cpx + (bid >> 3);
    const int bx = swz % gridDim.x;
    const int by = swz / gridDim.x;

    const int tid = threadIdx.x;
    const int lane = tid & 63;
    const int w = tid >> 6;
    const int wr = w >> 1, wc = w & 1;
    const int fr = lane & 15;
    const int kg = lane >> 4;

    const int brow = by * GBM;
    const int bcol = bx * GBN;

    const bf16_t* Ab = A + (long)brow * QLORA;
    const bf16_t* Bb = Bt + (long)bcol * QLORA;

    const int srow = w * 8 + (lane >> 3);
    const int scol = (((lane & 7) ^ (lane >> 3)) * 8);

    const uint rd_sw = (uint)((kg * 16) ^ ((fr & 7) << 4));
    const uint a_base = (uint)(uintptr_t)(&As[0][0]) + (uint)((wr * 64 + fr) * 128) + rd_sw;
    const uint b_base = (uint)(uintptr_t)(&Bs[0][0]) + (uint)((wc * 64 + fr) * 128) + rd_sw;

    f32x4 acc[4][4] = {};

    const int nt = QLORA / GBK;   // 24

    auto stage = [&](int buf, int k0) {
        #pragma unroll
        for (int it = 0; it < 4; it++) {
            const int r = it * 64 + srow;
            __builtin_amdgcn_global_load_lds(
                (const __attribute__((address_space(1))) void*)(Ab + (long)r * QLORA + k0 + scol),
                (__attribute__((address_space(3))) void*)(&As[buf][(it * 64 + w * 8) * GBK]),
                16, 0, 0);
        }
        #pragma unroll
        for (int it = 0; it < 2; it++) {
            const int r = it * 64 + srow;
            __builtin_amdgcn_global_load_lds(
                (const __attribute__((address_space(1))) void*)(Bb + (long)r * QLORA + k0 + scol),
                (__attribute__((address_space(3))) void*)(&Bs[buf][(it * 64 + w * 8) * GBK]),
                16, 0, 0);
        }
    };

    stage(0, 0);
    asm volatile("s_waitcnt vmcnt(0)" ::: "memory");
    __builtin_amdgcn_s_barrier();

    int cur = 0;
    for (int t = 0; t < nt; ++t) {
        if (t + 1 < nt) stage(cur ^ 1, (t + 1) * GBK);

        const uint aa = a_base + (uint)(cur * ABYTES);
        const uint bb = b_base + (uint)(cur * BBYTES);
        { GEMM_TILE_COMPUTE(aa, bb) }

        asm volatile("s_waitcnt vmcnt(0)" ::: "memory");
        __builtin_amdgcn_s_barrier();
        cur ^= 1;
    }

    // fused split_q epilogue: col%192 < 128 -> q_nope bf16; else rope -> q_out
    #pragma unroll
    for (int i = 0; i < 4; i++) {
        #pragma unroll
        for (int j = 0; j < 4; j++) {
            const int row0 = wr * 64 + i * 16 + kg * 4;
            const int col  = bcol + wc * 64 + j * 16 + fr;
            const int h  = col / 192;
            const int jj = col - h * 192;
            if (jj < 128) {
                #pragma unroll
                for (int r = 0; r < 4; r++) {
                    const int t = brow + row0 + r;
                    q_nope[((long)h * T_TOK + t) * NOPE_D + jj] = (bf16_t)acc[i][j][r];
                }
            } else {
                const int idx = jj - 128;
                const int j2 = idx >> 1;
                const int odd = idx & 1;
                #pragma unroll
                for (int r = 0; r < 4; r++) {
                    const int t = brow + row0 + r;
                    const float v = acc[i][j][r];
                    const float p = __shfl_xor(v, 1, 64);
                    const int pos = positions[t];
                    const float c = cos_sin[pos * 64 + j2];
                    const float s = cos_sin[pos * 64 + 32 + j2];
                    const float o = odd ? (v * c + p * s) : (v * c - p * s);
                    q_out[(long)t * 9216 + h * 576 + 512 + (odd ? 32 : 0) + j2] = o;
                }
            }
        }
    }
}

// ---------------- launcher ----------------

extern "C" void kernel_launch(void* const* d_in, const int* in_sizes, int n_in,
                              void* d_out, int out_size, void* d_ws, size_t ws_size,
                              hipStream_t stream)
{
    const float* hs       = (const float*)d_in[0];
    const int*   positions= (const int*)d_in[1];
    const float* w_qkv_a  = (const float*)d_in[2];
    const float* q_a_ln_w = (const float*)d_in[3];
    const float* w_q_b    = (const float*)d_in[4];
    const float* kv_a_ln_w= (const float*)d_in[5];
    const float* w_kc     = (const float*)d_in[6];
    const float* cos_sin  = (const float*)d_in[7];
    const float* k_cache_in  = (const float*)d_in[8];
    const float* rope_cache_in = (const float*)d_in[9];
    const int*   slot_map = (const int*)d_in[10];

    float* out   = (float*)d_out;
    float* q_out = out;                       // 4096*16*576
    float* k_out = out + 37748736;            // 4096*576
    float* kc_out = out + 40108032;           // 16384*512
    float* rc_out = out + 48496640;           // 16384*64

    char* ws = (char*)d_ws;
    // common region (live during GEMM1)
    bf16_t* hs_bf  = (bf16_t*)(ws + 0);            // 58,720,256 B
    bf16_t* wqkvaT = (bf16_t*)(ws + 58720256);     // 30,277,632 B
    bf16_t* wqbT   = (bf16_t*)(ws + 88997888);     //  9,437,184 B
    bf16_t* wkcT   = (bf16_t*)(ws + 98435072);     //  2,097,152 B
    float*  qkv0   = (float*)(ws + 100532224);     // 34,603,008 B

    const bool splitk = ws_size >= (size_t)169738240;

    float*  qkv1;
    bf16_t* q_a;
    bf16_t* q_nope;
    if (splitk) {
        qkv1   = (float*)(ws + 135135232);         // 34,603,008 B (dead after rmsq_kside)
        q_a    = (bf16_t*)(ws + 0);                // hs_bf region, dead after GEMM1
        q_nope = (bf16_t*)(ws + 135135232);        // reuse qkv1 slot after rmsq_kside
    } else {
        qkv1   = nullptr;
        q_a    = (bf16_t*)(ws + 135135232);
        q_nope = (bf16_t*)(ws + 100532224);        // reuse qkv0 slot
    }

    // caches: full copy, then scatter-overwrite in rmsq_kside
    hipMemcpyAsync(kc_out, k_cache_in, (size_t)16384 * 512 * 4, hipMemcpyDeviceToDevice, stream);
    hipMemcpyAsync(rc_out, rope_cache_in, (size_t)16384 * 64 * 4, hipMemcpyDeviceToDevice, stream);

    cast_f32_bf16<<<2048, 256, 0, stream>>>(hs, hs_bf, (long)T_TOK * H_DIM / 8);
    transpose_cast<<<dim3(NQKV / 32, H_DIM / 32), 256, 0, stream>>>(w_qkv_a, wqkvaT, H_DIM, NQKV);
    transpose_cast<<<dim3(NQB / 32, QLORA / 32), 256, 0, stream>>>(w_q_b, wqbT, QLORA, NQB);
    transpose_cast<<<dim3(512 / 32, 2048 / 32), 256, 0, stream>>>(w_kc, wkcT, 2048, 512);

    // GEMM1: qkv = hs @ w_qkv_a   (4096 x 2112, K=7168)
    if (splitk) {
        gemm_mfma<<<dim3((NQKV + GBN - 1) / GBN, T_TOK / GBM, 2), 512, 0, stream>>>(
            hs_bf, H_DIM, 3584, wqkvaT, H_DIM, 3584,
            qkv0, NQKV, (long)T_TOK * NQKV, 3584, NQKV);
    } else {
        gemm_mfma<<<dim3((NQKV + GBN - 1) / GBN, T_TOK / GBM, 1), 512, 0, stream>>>(
            hs_bf, H_DIM, 0, wqkvaT, H_DIM, 0, qkv0, NQKV, 0, H_DIM, NQKV);
    }

    rmsq_kside_kernel<<<T_TOK, 256, 0, stream>>>(qkv0, qkv1, q_a_ln_w, kv_a_ln_w,
                                                 cos_sin, positions, slot_map,
                                                 q_a, k_out, kc_out, rc_out);

    // GEMM2 + fused split_q: writes q_nope (bf16) and q_out[..., 512:576]
    gemm2_fused<<<dim3(NQB / GBN, T_TOK / GBM), 512, 0, stream>>>(
        q_a, wqbT, cos_sin, positions, q_nope, q_out);

    // GEMM3 (batched over heads): q_out[:, h, :512] = q_nope[h] @ w_kc[h]   (K=128)
    gemm_mfma<<<dim3(KVLORA / GBN, T_TOK / GBM, NHEAD), 512, 0, stream>>>(
        q_nope, NOPE_D, (long)T_TOK * NOPE_D,
        wkcT, 2048, 128,
        q_out, NHEAD * 576, 576, NOPE_D, KVLORA);
}

// Round 10
// 395.622 us; speedup vs baseline: 1.0735x; 1.0735x over previous
//
#include <hip/hip_runtime.h>
#include <hip/hip_bf16.h>

typedef __bf16 bf16_t;
typedef __bf16 bf16x8 __attribute__((ext_vector_type(8)));
typedef float f32x4 __attribute__((ext_vector_type(4)));
typedef unsigned int uint;

#define T_TOK 4096
#define H_DIM 7168
#define QLORA 1536
#define KVLORA 512
#define ROPE_D 64
#define NOPE_D 128
#define NHEAD 16
#define NQKV 2112   /* QLORA + KVLORA + ROPE */
#define NQB  3072   /* NHEAD * 192 */
#define EPS_F 1e-6f

// ---------------- elementwise helpers ----------------

__global__ void cast_f32_bf16(const float* __restrict__ in, bf16_t* __restrict__ out, long n8)
{
    long stride = (long)gridDim.x * blockDim.x;
    for (long i = (long)blockIdx.x * blockDim.x + threadIdx.x; i < n8; i += stride) {
        const float4 a = ((const float4*)in)[i * 2];
        const float4 b = ((const float4*)in)[i * 2 + 1];
        bf16x8 v;
        v[0] = (bf16_t)a.x; v[1] = (bf16_t)a.y; v[2] = (bf16_t)a.z; v[3] = (bf16_t)a.w;
        v[4] = (bf16_t)b.x; v[5] = (bf16_t)b.y; v[6] = (bf16_t)b.z; v[7] = (bf16_t)b.w;
        ((bf16x8*)out)[i] = v;
    }
}

// out[C][R] (bf16) = transpose of in[R][C] (f32)
__global__ __launch_bounds__(256) void transpose_cast(const float* __restrict__ in,
                                                      bf16_t* __restrict__ out, int R, int C)
{
    __shared__ float tile[32][33];
    const int bx = blockIdx.x * 32;   // col block of in
    const int by = blockIdx.y * 32;   // row block of in
    const int tx = threadIdx.x & 31, ty = threadIdx.x >> 5;
    #pragma unroll
    for (int r = ty; r < 32; r += 8)
        tile[r][tx] = in[(long)(by + r) * C + bx + tx];
    __syncthreads();
    #pragma unroll
    for (int r = ty; r < 32; r += 8)
        out[(long)(bx + r) * R + by + tx] = (bf16_t)tile[tx][r];
}

// block reduction safe for repeated use (leading+trailing barriers)
__device__ inline float block_sum_256(float v)
{
    #pragma unroll
    for (int off = 32; off > 0; off >>= 1) v += __shfl_xor(v, off, 64);
    __shared__ float tmp[4];
    __syncthreads();
    if ((threadIdx.x & 63) == 0) tmp[threadIdx.x >> 6] = v;
    __syncthreads();
    return tmp[0] + tmp[1] + tmp[2] + tmp[3];
}

// fused: RMS-norm q-lora -> bf16 q_a;  RMS-norm latent + rope -> k_out/caches
__global__ __launch_bounds__(256) void rmsq_kside_kernel(
    const float* __restrict__ qkv, const float* __restrict__ qkvB,
    const float* __restrict__ q_w, const float* __restrict__ kv_w,
    const float* __restrict__ cos_sin, const int* __restrict__ positions,
    const int* __restrict__ slot_map,
    bf16_t* __restrict__ q_a, float* __restrict__ k_out,
    float* __restrict__ kc_out, float* __restrict__ rc_out)
{
    const int t = blockIdx.x;
    const float* x = qkv + (long)t * NQKV;
    const float* xB = qkvB ? qkvB + (long)t * NQKV : nullptr;

    // ---- q side: 1536 elems, 6/thread ----
    float loc[6];
    float ss = 0.f;
    #pragma unroll
    for (int i = 0; i < 6; i++) {
        int idx = threadIdx.x + 256 * i;
        float v = x[idx];
        if (xB) v += xB[idx];
        loc[i] = v; ss += v * v;
    }
    ss = block_sum_256(ss);
    const float scq = rsqrtf(ss / (float)QLORA + EPS_F);
    #pragma unroll
    for (int i = 0; i < 6; i++) {
        int idx = threadIdx.x + 256 * i;
        q_a[(long)t * QLORA + idx] = (bf16_t)(loc[i] * scq * q_w[idx]);
    }

    // ---- k side: latent 512 + rope 64 ----
    const float* lat = x + QLORA;
    const float* latB = xB ? xB + QLORA : nullptr;
    float v0 = lat[threadIdx.x];
    float v1 = lat[threadIdx.x + 256];
    if (latB) { v0 += latB[threadIdx.x]; v1 += latB[threadIdx.x + 256]; }
    float ssk = v0 * v0 + v1 * v1;
    ssk = block_sum_256(ssk);
    const float sck = rsqrtf(ssk / (float)KVLORA + EPS_F);
    const int slot = slot_map[t];
    const float a0 = v0 * sck * kv_w[threadIdx.x];
    const float a1 = v1 * sck * kv_w[threadIdx.x + 256];
    k_out[(long)t * 576 + threadIdx.x]        = a0;
    k_out[(long)t * 576 + 256 + threadIdx.x]  = a1;
    kc_out[(long)slot * KVLORA + threadIdx.x]       = a0;
    kc_out[(long)slot * KVLORA + 256 + threadIdx.x] = a1;
    if (threadIdx.x < 32) {
        const int j = threadIdx.x;
        const int pos = positions[t];
        const float c = cos_sin[pos * 64 + j];
        const float s = cos_sin[pos * 64 + 32 + j];
        float x1 = lat[KVLORA + 2 * j];
        float x2 = lat[KVLORA + 2 * j + 1];
        if (latB) { x1 += latB[KVLORA + 2 * j]; x2 += latB[KVLORA + 2 * j + 1]; }
        const float o1 = x1 * c - x2 * s;
        const float o2 = x2 * c + x1 * s;
        k_out[(long)t * 576 + 512 + j]      = o1;
        k_out[(long)t * 576 + 512 + 32 + j] = o2;
        rc_out[(long)slot * 64 + j]      = o1;
        rc_out[(long)slot * 64 + 32 + j] = o2;
    }
}

// ------- 256x128-tile, BK=32, 2-phase dbuf bf16 MFMA GEMM, swizzled LDS ------
// C(MxN f32) = A(MxK bf16) * B^T(NxK bf16); M%256==0, K%64==0; N edge clamped.
// 8 waves in 4Mx2N grid, wave tile 64x64 (4x4 acc = 16 MFMA/K-step(32),
// 8 ds_read_b128 -> 0.5 reads/MFMA; LDS traffic 42KB/MFLOP vs 61 at 128^2).
// LDS = 2 x (16+8) KB = 48 KB -> 2+ blocks/CU (the 2-phase structure's
// requirement, r6/r7/r9 lesson). Same verified sync skeleton as r5/r8: stage
// next tile BEFORE compute, one vmcnt(0)+barrier per K-step.
// Bank swizzle (rule #21, both sides) for 64B rows (4 x 16B chunks):
// physical chunk c_p of row r holds global chunk c_p ^ (r&3); write side
// pre-swizzles the GLOBAL chunk: (lane&3) ^ ((lane>>2)&3); read side:
// base = row*64 + ((kg ^ (row&3))*16). Row sets differ by multiples of 16
// rows so (row&3) is per-thread invariant -> offset immediates stay valid.
#define GBM 256
#define GBN 128
#define GBK 32
#define ABYTES (GBM * GBK * 2)   /* 16 KB per A buffer */
#define BBYTES (GBN * GBK * 2)   /*  8 KB per B buffer */

// per-K-step compute: 8 swizzled ds_read_b128 + 16 MFMA (single MFMA-K)
#define GEMM_TILE_COMPUTE(aa, bb)                                                            \
    bf16x8 aV0, aV1, aV2, aV3, bV0, bV1, bV2, bV3;                                           \
    asm volatile("ds_read_b128 %0, %1 offset:0"    : "=v"(aV0) : "v"(aa));                   \
    asm volatile("ds_read_b128 %0, %1 offset:1024" : "=v"(aV1) : "v"(aa));                   \
    asm volatile("ds_read_b128 %0, %1 offset:2048" : "=v"(aV2) : "v"(aa));                   \
    asm volatile("ds_read_b128 %0, %1 offset:3072" : "=v"(aV3) : "v"(aa));                   \
    asm volatile("ds_read_b128 %0, %1 offset:0"    : "=v"(bV0) : "v"(bb));                   \
    asm volatile("ds_read_b128 %0, %1 offset:1024" : "=v"(bV1) : "v"(bb));                   \
    asm volatile("ds_read_b128 %0, %1 offset:2048" : "=v"(bV2) : "v"(bb));                   \
    asm volatile("ds_read_b128 %0, %1 offset:3072" : "=v"(bV3) : "v"(bb));                   \
    asm volatile("s_waitcnt lgkmcnt(0)" ::: "memory");                                       \
    __builtin_amdgcn_sched_barrier(0);                                                       \
    acc[0][0] = __builtin_amdgcn_mfma_f32_16x16x32_bf16(aV0, bV0, acc[0][0], 0, 0, 0);       \
    acc[0][1] = __builtin_amdgcn_mfma_f32_16x16x32_bf16(aV0, bV1, acc[0][1], 0, 0, 0);       \
    acc[0][2] = __builtin_amdgcn_mfma_f32_16x16x32_bf16(aV0, bV2, acc[0][2], 0, 0, 0);       \
    acc[0][3] = __builtin_amdgcn_mfma_f32_16x16x32_bf16(aV0, bV3, acc[0][3], 0, 0, 0);       \
    acc[1][0] = __builtin_amdgcn_mfma_f32_16x16x32_bf16(aV1, bV0, acc[1][0], 0, 0, 0);       \
    acc[1][1] = __builtin_amdgcn_mfma_f32_16x16x32_bf16(aV1, bV1, acc[1][1], 0, 0, 0);       \
    acc[1][2] = __builtin_amdgcn_mfma_f32_16x16x32_bf16(aV1, bV2, acc[1][2], 0, 0, 0);       \
    acc[1][3] = __builtin_amdgcn_mfma_f32_16x16x32_bf16(aV1, bV3, acc[1][3], 0, 0, 0);       \
    acc[2][0] = __builtin_amdgcn_mfma_f32_16x16x32_bf16(aV2, bV0, acc[2][0], 0, 0, 0);       \
    acc[2][1] = __builtin_amdgcn_mfma_f32_16x16x32_bf16(aV2, bV1, acc[2][1], 0, 0, 0);       \
    acc[2][2] = __builtin_amdgcn_mfma_f32_16x16x32_bf16(aV2, bV2, acc[2][2], 0, 0, 0);       \
    acc[2][3] = __builtin_amdgcn_mfma_f32_16x16x32_bf16(aV2, bV3, acc[2][3], 0, 0, 0);       \
    acc[3][0] = __builtin_amdgcn_mfma_f32_16x16x32_bf16(aV3, bV0, acc[3][0], 0, 0, 0);       \
    acc[3][1] = __builtin_amdgcn_mfma_f32_16x16x32_bf16(aV3, bV1, acc[3][1], 0, 0, 0);       \
    acc[3][2] = __builtin_amdgcn_mfma_f32_16x16x32_bf16(aV3, bV2, acc[3][2], 0, 0, 0);       \
    acc[3][3] = __builtin_amdgcn_mfma_f32_16x16x32_bf16(aV3, bV3, acc[3][3], 0, 0, 0);

__global__ __launch_bounds__(512) void gemm_mfma(
    const bf16_t* __restrict__ A, int lda, long sA,
    const bf16_t* __restrict__ Bt, int ldb, long sB,
    float* __restrict__ C, int ldc, long sC,
    int K, int N)
{
    __shared__ bf16_t As[2][GBM * GBK];   // 2 x 16 KB
    __shared__ bf16_t Bs[2][GBN * GBK];   // 2 x 8 KB

    const int nwg = gridDim.x * gridDim.y;
    const int bid = blockIdx.y * gridDim.x + blockIdx.x;
    const int cpx = nwg >> 3;
    const int swz = (bid & 7) * cpx + (bid >> 3);
    const int bx = swz % gridDim.x;
    const int by = swz / gridDim.x;

    const int tid = threadIdx.x;
    const int lane = tid & 63;
    const int w = tid >> 6;            // 0..7
    const int wr = w >> 1, wc = w & 1; // 4Mx2N wave grid; wave tile 64x64
    const int fr = lane & 15;
    const int kg = lane >> 4;          // 0..3 == 16B chunk within 64B row

    const long brow = (long)by * GBM;
    const long bcol = (long)bx * GBN;

    const bf16_t* Ab = A + blockIdx.z * sA + brow * lda;
    const bf16_t* Bb = Bt + blockIdx.z * sB;
    float* Cb = C + blockIdx.z * sC + brow * ldc;

    // staging: issue = 1 KB = 16 rows x 64B; lane -> row=lane>>2, chunk=lane&3.
    // A: 16 KB = 16 issues (2/wave); B: 8 KB = 8 issues (1/wave).
    const int sr0  = w * 16 + (lane >> 2);
    const int scol = (((lane & 3) ^ ((lane >> 2) & 3)) * 8);   // pre-swizzled global chunk

    const uint rd_sw  = (uint)((kg ^ (fr & 3)) * 16);
    const uint a_base = (uint)(uintptr_t)(&As[0][0]) + (uint)((wr * 64 + fr) * 64) + rd_sw;
    const uint b_base = (uint)(uintptr_t)(&Bs[0][0]) + (uint)((wc * 64 + fr) * 64) + rd_sw;

    f32x4 acc[4][4] = {};

    const int nt = K / GBK;

    auto stage = [&](int buf, int k0) {
        #pragma unroll
        for (int it = 0; it < 2; it++) {
            const int r = it * 128 + sr0;
            __builtin_amdgcn_global_load_lds(
                (const __attribute__((address_space(1))) void*)(Ab + (long)r * lda + k0 + scol),
                (__attribute__((address_space(3))) void*)(&As[buf][(it * 128 + w * 16) * GBK]),
                16, 0, 0);
        }
        {
            long bn = bcol + sr0; if (bn >= N) bn = N - 1;   // clamp; masked at store
            __builtin_amdgcn_global_load_lds(
                (const __attribute__((address_space(1))) void*)(Bb + bn * ldb + k0 + scol),
                (__attribute__((address_space(3))) void*)(&Bs[buf][(w * 16) * GBK]),
                16, 0, 0);
        }
    };

    stage(0, 0);
    asm volatile("s_waitcnt vmcnt(0)" ::: "memory");
    __builtin_amdgcn_s_barrier();

    int cur = 0;
    for (int t = 0; t < nt; ++t) {
        if (t + 1 < nt) stage(cur ^ 1, (t + 1) * GBK);

        const uint aa = a_base + (uint)(cur * ABYTES);
        const uint bb = b_base + (uint)(cur * BBYTES);
        { GEMM_TILE_COMPUTE(aa, bb) }

        asm volatile("s_waitcnt vmcnt(0)" ::: "memory");
        __builtin_amdgcn_s_barrier();
        cur ^= 1;
    }

    // C/D layout: col = lane&15, row = (lane>>4)*4 + reg
    #pragma unroll
    for (int i = 0; i < 4; i++) {
        #pragma unroll
        for (int j = 0; j < 4; j++) {
            const int row0 = wr * 64 + i * 16 + kg * 4;
            const long col = bcol + wc * 64 + j * 16 + fr;
            if (col < N) {
                #pragma unroll
                for (int r = 0; r < 4; r++)
                    Cb[(long)(row0 + r) * ldc + col] = acc[i][j][r];
            }
        }
    }
}

// ---------------- GEMM2 with fused split_q epilogue (256x128, BK=32) ---------
__global__ __launch_bounds__(512) void gemm2_fused(
    const bf16_t* __restrict__ A,   // q_a, lda=QLORA
    const bf16_t* __restrict__ Bt,  // wqbT, ldb=QLORA
    const float* __restrict__ cos_sin,
    const int* __restrict__ positions,
    bf16_t* __restrict__ q_nope,
    float* __restrict__ q_out)
{
    __shared__ bf16_t As[2][GBM * GBK];
    __shared__ bf16_t Bs[2][GBN * GBK];

    const int nwg = gridDim.x * gridDim.y;
    const int bid = blockIdx.y * gridDim.x + blockIdx.x;
    const int cpx = nwg >> 3;
    const int swz = (bid & 7) * cpx + (bid >> 3);
    const int bx = swz % gridDim.x;
    const int by = swz / gridDim.x;

    const int tid = threadIdx.x;
    const int lane = tid & 63;
    const int w = tid >> 6;
    const int wr = w >> 1, wc = w & 1;
    const int fr = lane & 15;
    const int kg = lane >> 4;

    const int brow = by * GBM;
    const int bcol = bx * GBN;

    const bf16_t* Ab = A + (long)brow * QLORA;
    const bf16_t* Bb = Bt + (long)bcol * QLORA;

    const int sr0  = w * 16 + (lane >> 2);
    const int scol = (((lane & 3) ^ ((lane >> 2) & 3)) * 8);

    const uint rd_sw  = (uint)((kg ^ (fr & 3)) * 16);
    const uint a_base = (uint)(uintptr_t)(&As[0][0]) + (uint)((wr * 64 + fr) * 64) + rd_sw;
    const uint b_base = (uint)(uintptr_t)(&Bs[0][0]) + (uint)((wc * 64 + fr) * 64) + rd_sw;

    f32x4 acc[4][4] = {};

    const int nt = QLORA / GBK;   // 48

    auto stage = [&](int buf, int k0) {
        #pragma unroll
        for (int it = 0; it < 2; it++) {
            const int r = it * 128 + sr0;
            __builtin_amdgcn_global_load_lds(
                (const __attribute__((address_space(1))) void*)(Ab + (long)r * QLORA + k0 + scol),
                (__attribute__((address_space(3))) void*)(&As[buf][(it * 128 + w * 16) * GBK]),
                16, 0, 0);
        }
        __builtin_amdgcn_global_load_lds(
            (const __attribute__((address_space(1))) void*)(Bb + (long)sr0 * QLORA + k0 + scol),
            (__attribute__((address_space(3))) void*)(&Bs[buf][(w * 16) * GBK]),
            16, 0, 0);
    };

    stage(0, 0);
    asm volatile("s_waitcnt vmcnt(0)" ::: "memory");
    __builtin_amdgcn_s_barrier();

    int cur = 0;
    for (int t = 0; t < nt; ++t) {
        if (t + 1 < nt) stage(cur ^ 1, (t + 1) * GBK);

        const uint aa = a_base + (uint)(cur * ABYTES);
        const uint bb = b_base + (uint)(cur * BBYTES);
        { GEMM_TILE_COMPUTE(aa, bb) }

        asm volatile("s_waitcnt vmcnt(0)" ::: "memory");
        __builtin_amdgcn_s_barrier();
        cur ^= 1;
    }

    // fused split_q epilogue: col%192 < 128 -> q_nope bf16; else rope -> q_out
    #pragma unroll
    for (int i = 0; i < 4; i++) {
        #pragma unroll
        for (int j = 0; j < 4; j++) {
            const int row0 = wr * 64 + i * 16 + kg * 4;
            const int col  = bcol + wc * 64 + j * 16 + fr;
            const int h  = col / 192;
            const int jj = col - h * 192;
            if (jj < 128) {
                #pragma unroll
                for (int r = 0; r < 4; r++) {
                    const int t = brow + row0 + r;
                    q_nope[((long)h * T_TOK + t) * NOPE_D + jj] = (bf16_t)acc[i][j][r];
                }
            } else {
                const int idx = jj - 128;
                const int j2 = idx >> 1;
                const int odd = idx & 1;
                #pragma unroll
                for (int r = 0; r < 4; r++) {
                    const int t = brow + row0 + r;
                    const float v = acc[i][j][r];
                    const float p = __shfl_xor(v, 1, 64);
                    const int pos = positions[t];
                    const float c = cos_sin[pos * 64 + j2];
                    const float s = cos_sin[pos * 64 + 32 + j2];
                    const float o = odd ? (v * c + p * s) : (v * c - p * s);
                    q_out[(long)t * 9216 + h * 576 + 512 + (odd ? 32 : 0) + j2] = o;
                }
            }
        }
    }
}

// ---------------- launcher ----------------

extern "C" void kernel_launch(void* const* d_in, const int* in_sizes, int n_in,
                              void* d_out, int out_size, void* d_ws, size_t ws_size,
                              hipStream_t stream)
{
    const float* hs       = (const float*)d_in[0];
    const int*   positions= (const int*)d_in[1];
    const float* w_qkv_a  = (const float*)d_in[2];
    const float* q_a_ln_w = (const float*)d_in[3];
    const float* w_q_b    = (const float*)d_in[4];
    const float* kv_a_ln_w= (const float*)d_in[5];
    const float* w_kc     = (const float*)d_in[6];
    const float* cos_sin  = (const float*)d_in[7];
    const float* k_cache_in  = (const float*)d_in[8];
    const float* rope_cache_in = (const float*)d_in[9];
    const int*   slot_map = (const int*)d_in[10];

    float* out   = (float*)d_out;
    float* q_out = out;                       // 4096*16*576
    float* k_out = out + 37748736;            // 4096*576
    float* kc_out = out + 40108032;           // 16384*512
    float* rc_out = out + 48496640;           // 16384*64

    char* ws = (char*)d_ws;
    // common region (live during GEMM1)
    bf16_t* hs_bf  = (bf16_t*)(ws + 0);            // 58,720,256 B
    bf16_t* wqkvaT = (bf16_t*)(ws + 58720256);     // 30,277,632 B
    bf16_t* wqbT   = (bf16_t*)(ws + 88997888);     //  9,437,184 B
    bf16_t* wkcT   = (bf16_t*)(ws + 98435072);     //  2,097,152 B
    float*  qkv0   = (float*)(ws + 100532224);     // 34,603,008 B

    const bool splitk = ws_size >= (size_t)169738240;

    float*  qkv1;
    bf16_t* q_a;
    bf16_t* q_nope;
    if (splitk) {
        qkv1   = (float*)(ws + 135135232);         // 34,603,008 B (dead after rmsq_kside)
        q_a    = (bf16_t*)(ws + 0);                // hs_bf region, dead after GEMM1
        q_nope = (bf16_t*)(ws + 135135232);        // reuse qkv1 slot after rmsq_kside
    } else {
        qkv1   = nullptr;
        q_a    = (bf16_t*)(ws + 135135232);
        q_nope = (bf16_t*)(ws + 100532224);        // reuse qkv0 slot
    }

    // caches: full copy, then scatter-overwrite in rmsq_kside
    hipMemcpyAsync(kc_out, k_cache_in, (size_t)16384 * 512 * 4, hipMemcpyDeviceToDevice, stream);
    hipMemcpyAsync(rc_out, rope_cache_in, (size_t)16384 * 64 * 4, hipMemcpyDeviceToDevice, stream);

    cast_f32_bf16<<<2048, 256, 0, stream>>>(hs, hs_bf, (long)T_TOK * H_DIM / 8);
    transpose_cast<<<dim3(NQKV / 32, H_DIM / 32), 256, 0, stream>>>(w_qkv_a, wqkvaT, H_DIM, NQKV);
    transpose_cast<<<dim3(NQB / 32, QLORA / 32), 256, 0, stream>>>(w_q_b, wqbT, QLORA, NQB);
    transpose_cast<<<dim3(512 / 32, 2048 / 32), 256, 0, stream>>>(w_kc, wkcT, 2048, 512);

    // GEMM1: qkv = hs @ w_qkv_a   (4096 x 2112, K=7168)
    if (splitk) {
        gemm_mfma<<<dim3((NQKV + GBN - 1) / GBN, T_TOK / GBM, 2), 512, 0, stream>>>(
            hs_bf, H_DIM, 3584, wqkvaT, H_DIM, 3584,
            qkv0, NQKV, (long)T_TOK * NQKV, 3584, NQKV);
    } else {
        gemm_mfma<<<dim3((NQKV + GBN - 1) / GBN, T_TOK / GBM, 1), 512, 0, stream>>>(
            hs_bf, H_DIM, 0, wqkvaT, H_DIM, 0, qkv0, NQKV, 0, H_DIM, NQKV);
    }

    rmsq_kside_kernel<<<T_TOK, 256, 0, stream>>>(qkv0, qkv1, q_a_ln_w, kv_a_ln_w,
                                                 cos_sin, positions, slot_map,
                                                 q_a, k_out, kc_out, rc_out);

    // GEMM2 + fused split_q: writes q_nope (bf16) and q_out[..., 512:576]
    gemm2_fused<<<dim3(NQB / GBN, T_TOK / GBM), 512, 0, stream>>>(
        q_a, wqbT, cos_sin, positions, q_nope, q_out);

    // GEMM3 (batched over heads): q_out[:, h, :512] = q_nope[h] @ w_kc[h]   (K=128, nt=4)
    gemm_mfma<<<dim3(KVLORA / GBN, T_TOK / GBM, NHEAD), 512, 0, stream>>>(
        q_nope, NOPE_D, (long)T_TOK * NOPE_D,
        wkcT, 2048, 128,
        q_out, NHEAD * 576, 576, NOPE_D, KVLORA);
}

// Round 11
// 367.785 us; speedup vs baseline: 1.1548x; 1.0757x over previous
//
#include <hip/hip_runtime.h>
#include <hip/hip_bf16.h>

typedef __bf16 bf16_t;
typedef __bf16 bf16x8 __attribute__((ext_vector_type(8)));
typedef float f32x4 __attribute__((ext_vector_type(4)));
typedef unsigned int uint;

#define T_TOK 4096
#define H_DIM 7168
#define QLORA 1536
#define KVLORA 512
#define ROPE_D 64
#define NOPE_D 128
#define NHEAD 16
#define NQKV 2112   /* QLORA + KVLORA + ROPE */
#define NQB  3072   /* NHEAD * 192 */
#define EPS_F 1e-6f

// ---------------- elementwise helpers ----------------

__global__ void cast_f32_bf16(const float* __restrict__ in, bf16_t* __restrict__ out, long n8)
{
    long stride = (long)gridDim.x * blockDim.x;
    for (long i = (long)blockIdx.x * blockDim.x + threadIdx.x; i < n8; i += stride) {
        const float4 a = ((const float4*)in)[i * 2];
        const float4 b = ((const float4*)in)[i * 2 + 1];
        bf16x8 v;
        v[0] = (bf16_t)a.x; v[1] = (bf16_t)a.y; v[2] = (bf16_t)a.z; v[3] = (bf16_t)a.w;
        v[4] = (bf16_t)b.x; v[5] = (bf16_t)b.y; v[6] = (bf16_t)b.z; v[7] = (bf16_t)b.w;
        ((bf16x8*)out)[i] = v;
    }
}

// out[C][R] (bf16) = transpose of in[R][C] (f32)
__global__ __launch_bounds__(256) void transpose_cast(const float* __restrict__ in,
                                                      bf16_t* __restrict__ out, int R, int C)
{
    __shared__ float tile[32][33];
    const int bx = blockIdx.x * 32;   // col block of in
    const int by = blockIdx.y * 32;   // row block of in
    const int tx = threadIdx.x & 31, ty = threadIdx.x >> 5;
    #pragma unroll
    for (int r = ty; r < 32; r += 8)
        tile[r][tx] = in[(long)(by + r) * C + bx + tx];
    __syncthreads();
    #pragma unroll
    for (int r = ty; r < 32; r += 8)
        out[(long)(bx + r) * R + by + tx] = (bf16_t)tile[tx][r];
}

// block reduction safe for repeated use (leading+trailing barriers)
__device__ inline float block_sum_256(float v)
{
    #pragma unroll
    for (int off = 32; off > 0; off >>= 1) v += __shfl_xor(v, off, 64);
    __shared__ float tmp[4];
    __syncthreads();
    if ((threadIdx.x & 63) == 0) tmp[threadIdx.x >> 6] = v;
    __syncthreads();
    return tmp[0] + tmp[1] + tmp[2] + tmp[3];
}

// fused: RMS-norm q-lora -> bf16 q_a;  RMS-norm latent + rope -> k_out/caches
__global__ __launch_bounds__(256) void rmsq_kside_kernel(
    const float* __restrict__ qkv, const float* __restrict__ qkvB,
    const float* __restrict__ q_w, const float* __restrict__ kv_w,
    const float* __restrict__ cos_sin, const int* __restrict__ positions,
    const int* __restrict__ slot_map,
    bf16_t* __restrict__ q_a, float* __restrict__ k_out,
    float* __restrict__ kc_out, float* __restrict__ rc_out)
{
    const int t = blockIdx.x;
    const float* x = qkv + (long)t * NQKV;
    const float* xB = qkvB ? qkvB + (long)t * NQKV : nullptr;

    // ---- q side: 1536 elems, 6/thread ----
    float loc[6];
    float ss = 0.f;
    #pragma unroll
    for (int i = 0; i < 6; i++) {
        int idx = threadIdx.x + 256 * i;
        float v = x[idx];
        if (xB) v += xB[idx];
        loc[i] = v; ss += v * v;
    }
    ss = block_sum_256(ss);
    const float scq = rsqrtf(ss / (float)QLORA + EPS_F);
    #pragma unroll
    for (int i = 0; i < 6; i++) {
        int idx = threadIdx.x + 256 * i;
        q_a[(long)t * QLORA + idx] = (bf16_t)(loc[i] * scq * q_w[idx]);
    }

    // ---- k side: latent 512 + rope 64 ----
    const float* lat = x + QLORA;
    const float* latB = xB ? xB + QLORA : nullptr;
    float v0 = lat[threadIdx.x];
    float v1 = lat[threadIdx.x + 256];
    if (latB) { v0 += latB[threadIdx.x]; v1 += latB[threadIdx.x + 256]; }
    float ssk = v0 * v0 + v1 * v1;
    ssk = block_sum_256(ssk);
    const float sck = rsqrtf(ssk / (float)KVLORA + EPS_F);
    const int slot = slot_map[t];
    const float a0 = v0 * sck * kv_w[threadIdx.x];
    const float a1 = v1 * sck * kv_w[threadIdx.x + 256];
    k_out[(long)t * 576 + threadIdx.x]        = a0;
    k_out[(long)t * 576 + 256 + threadIdx.x]  = a1;
    kc_out[(long)slot * KVLORA + threadIdx.x]       = a0;
    kc_out[(long)slot * KVLORA + 256 + threadIdx.x] = a1;
    if (threadIdx.x < 32) {
        const int j = threadIdx.x;
        const int pos = positions[t];
        const float c = cos_sin[pos * 64 + j];
        const float s = cos_sin[pos * 64 + 32 + j];
        float x1 = lat[KVLORA + 2 * j];
        float x2 = lat[KVLORA + 2 * j + 1];
        if (latB) { x1 += latB[KVLORA + 2 * j]; x2 += latB[KVLORA + 2 * j + 1]; }
        const float o1 = x1 * c - x2 * s;
        const float o2 = x2 * c + x1 * s;
        k_out[(long)t * 576 + 512 + j]      = o1;
        k_out[(long)t * 576 + 512 + 32 + j] = o2;
        rc_out[(long)slot * 64 + j]      = o1;
        rc_out[(long)slot * 64 + 32 + j] = o2;
    }
}

// ---------------- r8 GEMM: 2-phase dbuf bf16 MFMA, bank-swizzled LDS ----------
// C(MxN f32) = A(MxK bf16) * B^T(NxK bf16); M%128==0, K%64==0; N edge clamped.
// 128x128 tile, BK=64, 8 waves (2Mx4N, wave tile 64x32, 4x2 acc), gload_lds
// staging into 2-buf LDS; next tile staged BEFORE compute; one vmcnt(0)+barrier
// per K-step. Bank swizzle (rule #21, both sides): physical col byte c of row r
// at c ^ ((r&7)<<4); write side pre-swizzles the GLOBAL col chunk; read side
// XORs the frag base; ks=1 = base ^ 64.
#define GBM 128
#define GBN 128
#define GBK 64

__global__ __launch_bounds__(512) void gemm_mfma(
    const bf16_t* __restrict__ A, int lda, long sA,
    const bf16_t* __restrict__ Bt, int ldb, long sB,
    float* __restrict__ C, int ldc, long sC,
    int K, int N)
{
    __shared__ bf16_t As[2][GBM * GBK];   // 2 x 16 KB
    __shared__ bf16_t Bs[2][GBN * GBK];   // 2 x 16 KB

    const int nwg = gridDim.x * gridDim.y;
    const int bid = blockIdx.y * gridDim.x + blockIdx.x;
    const int cpx = nwg >> 3;
    const int swz = (bid & 7) * cpx + (bid >> 3);
    const int bx = swz % gridDim.x;
    const int by = swz / gridDim.x;

    const int tid = threadIdx.x;
    const int lane = tid & 63;
    const int w = tid >> 6;            // 0..7
    const int wr = w >> 2, wc = w & 3; // 2x4 wave grid; wave tile 64x32
    const int fr = lane & 15;
    const int kg = lane >> 4;

    const long brow = (long)by * GBM;
    const long bcol = (long)bx * GBN;

    const bf16_t* Ab = A + blockIdx.z * sA + brow * lda;
    const bf16_t* Bb = Bt + blockIdx.z * sB;
    float* Cb = C + blockIdx.z * sC + brow * ldc;

    const int srow = w * 16 + (lane >> 3);
    const int scol = (((lane & 7) ^ (lane >> 3)) * 8);

    const uint rd_sw = (uint)((kg * 16) ^ ((fr & 7) << 4));
    const uint a_base = (uint)(uintptr_t)(&As[0][0]) + (uint)((wr * 64 + fr) * 128) + rd_sw;
    const uint b_base = (uint)(uintptr_t)(&Bs[0][0]) + (uint)((wc * 32 + fr) * 128) + rd_sw;

    f32x4 acc[4][2] = {};

    const int nt = K / GBK;

    auto stage = [&](int buf, int k0) {
        #pragma unroll
        for (int it = 0; it < 2; it++) {
            const int r = srow + it * 8;
            __builtin_amdgcn_global_load_lds(
                (const __attribute__((address_space(1))) void*)(Ab + (long)r * lda + k0 + scol),
                (__attribute__((address_space(3))) void*)(&As[buf][(w * 16 + it * 8) * GBK]),
                16, 0, 0);
        }
        #pragma unroll
        for (int it = 0; it < 2; it++) {
            const int r = srow + it * 8;
            long bn = bcol + r; if (bn >= N) bn = N - 1;
            __builtin_amdgcn_global_load_lds(
                (const __attribute__((address_space(1))) void*)(Bb + bn * ldb + k0 + scol),
                (__attribute__((address_space(3))) void*)(&Bs[buf][(w * 16 + it * 8) * GBK]),
                16, 0, 0);
        }
    };

    stage(0, 0);
    asm volatile("s_waitcnt vmcnt(0)" ::: "memory");
    __builtin_amdgcn_s_barrier();

    int cur = 0;
    for (int t = 0; t < nt; ++t) {
        if (t + 1 < nt) stage(cur ^ 1, (t + 1) * GBK);

        const uint aa  = a_base + (uint)(cur * (GBM * GBK * 2));
        const uint bb  = b_base + (uint)(cur * (GBN * GBK * 2));
        const uint aaX = aa ^ 64u;
        const uint bbX = bb ^ 64u;
        bf16x8 a00, a01, a02, a03, a10, a11, a12, a13, b00, b01, b10, b11;
        asm volatile("ds_read_b128 %0, %1 offset:0"    : "=v"(a00) : "v"(aa));
        asm volatile("ds_read_b128 %0, %1 offset:2048" : "=v"(a01) : "v"(aa));
        asm volatile("ds_read_b128 %0, %1 offset:4096" : "=v"(a02) : "v"(aa));
        asm volatile("ds_read_b128 %0, %1 offset:6144" : "=v"(a03) : "v"(aa));
        asm volatile("ds_read_b128 %0, %1 offset:0"    : "=v"(a10) : "v"(aaX));
        asm volatile("ds_read_b128 %0, %1 offset:2048" : "=v"(a11) : "v"(aaX));
        asm volatile("ds_read_b128 %0, %1 offset:4096" : "=v"(a12) : "v"(aaX));
        asm volatile("ds_read_b128 %0, %1 offset:6144" : "=v"(a13) : "v"(aaX));
        asm volatile("ds_read_b128 %0, %1 offset:0"    : "=v"(b00) : "v"(bb));
        asm volatile("ds_read_b128 %0, %1 offset:2048" : "=v"(b01) : "v"(bb));
        asm volatile("ds_read_b128 %0, %1 offset:0"    : "=v"(b10) : "v"(bbX));
        asm volatile("ds_read_b128 %0, %1 offset:2048" : "=v"(b11) : "v"(bbX));
        asm volatile("s_waitcnt lgkmcnt(0)" ::: "memory");
        __builtin_amdgcn_sched_barrier(0);

        acc[0][0] = __builtin_amdgcn_mfma_f32_16x16x32_bf16(a00, b00, acc[0][0], 0, 0, 0);
        acc[0][1] = __builtin_amdgcn_mfma_f32_16x16x32_bf16(a00, b01, acc[0][1], 0, 0, 0);
        acc[1][0] = __builtin_amdgcn_mfma_f32_16x16x32_bf16(a01, b00, acc[1][0], 0, 0, 0);
        acc[1][1] = __builtin_amdgcn_mfma_f32_16x16x32_bf16(a01, b01, acc[1][1], 0, 0, 0);
        acc[2][0] = __builtin_amdgcn_mfma_f32_16x16x32_bf16(a02, b00, acc[2][0], 0, 0, 0);
        acc[2][1] = __builtin_amdgcn_mfma_f32_16x16x32_bf16(a02, b01, acc[2][1], 0, 0, 0);
        acc[3][0] = __builtin_amdgcn_mfma_f32_16x16x32_bf16(a03, b00, acc[3][0], 0, 0, 0);
        acc[3][1] = __builtin_amdgcn_mfma_f32_16x16x32_bf16(a03, b01, acc[3][1], 0, 0, 0);
        acc[0][0] = __builtin_amdgcn_mfma_f32_16x16x32_bf16(a10, b10, acc[0][0], 0, 0, 0);
        acc[0][1] = __builtin_amdgcn_mfma_f32_16x16x32_bf16(a10, b11, acc[0][1], 0, 0, 0);
        acc[1][0] = __builtin_amdgcn_mfma_f32_16x16x32_bf16(a11, b10, acc[1][0], 0, 0, 0);
        acc[1][1] = __builtin_amdgcn_mfma_f32_16x16x32_bf16(a11, b11, acc[1][1], 0, 0, 0);
        acc[2][0] = __builtin_amdgcn_mfma_f32_16x16x32_bf16(a12, b10, acc[2][0], 0, 0, 0);
        acc[2][1] = __builtin_amdgcn_mfma_f32_16x16x32_bf16(a12, b11, acc[2][1], 0, 0, 0);
        acc[3][0] = __builtin_amdgcn_mfma_f32_16x16x32_bf16(a13, b10, acc[3][0], 0, 0, 0);
        acc[3][1] = __builtin_amdgcn_mfma_f32_16x16x32_bf16(a13, b11, acc[3][1], 0, 0, 0);

        asm volatile("s_waitcnt vmcnt(0)" ::: "memory");
        __builtin_amdgcn_s_barrier();
        cur ^= 1;
    }

    #pragma unroll
    for (int i = 0; i < 4; i++) {
        #pragma unroll
        for (int j = 0; j < 2; j++) {
            const int row0 = wr * 64 + i * 16 + kg * 4;
            const long col = bcol + wc * 32 + j * 16 + fr;
            if (col < N) {
                #pragma unroll
                for (int r = 0; r < 4; r++)
                    Cb[(long)(row0 + r) * ldc + col] = acc[i][j][r];
            }
        }
    }
}

// ---------------- GEMM2 with fused split_q epilogue -------------------------
__global__ __launch_bounds__(512) void gemm2_fused(
    const bf16_t* __restrict__ A,   // q_a, lda=QLORA
    const bf16_t* __restrict__ Bt,  // wqbT, ldb=QLORA
    const float* __restrict__ cos_sin,
    const int* __restrict__ positions,
    bf16_t* __restrict__ q_nope,
    float* __restrict__ q_out)
{
    __shared__ bf16_t As[2][GBM * GBK];
    __shared__ bf16_t Bs[2][GBN * GBK];

    const int nwg = gridDim.x * gridDim.y;
    const int bid = blockIdx.y * gridDim.x + blockIdx.x;
    const int cpx = nwg >> 3;
    const int swz = (bid & 7) * cpx + (bid >> 3);
    const int bx = swz % gridDim.x;
    const int by = swz / gridDim.x;

    const int tid = threadIdx.x;
    const int lane = tid & 63;
    const int w = tid >> 6;
    const int wr = w >> 2, wc = w & 3;
    const int fr = lane & 15;
    const int kg = lane >> 4;

    const int brow = by * GBM;
    const int bcol = bx * GBN;

    const bf16_t* Ab = A + (long)brow * QLORA;
    const bf16_t* Bb = Bt + (long)bcol * QLORA;

    const int srow = w * 16 + (lane >> 3);
    const int scol = (((lane & 7) ^ (lane >> 3)) * 8);

    const uint rd_sw = (uint)((kg * 16) ^ ((fr & 7) << 4));
    const uint a_base = (uint)(uintptr_t)(&As[0][0]) + (uint)((wr * 64 + fr) * 128) + rd_sw;
    const uint b_base = (uint)(uintptr_t)(&Bs[0][0]) + (uint)((wc * 32 + fr) * 128) + rd_sw;

    f32x4 acc[4][2] = {};

    const int nt = QLORA / GBK;   // 24

    auto stage = [&](int buf, int k0) {
        #pragma unroll
        for (int it = 0; it < 2; it++) {
            const int r = srow + it * 8;
            __builtin_amdgcn_global_load_lds(
                (const __attribute__((address_space(1))) void*)(Ab + (long)r * QLORA + k0 + scol),
                (__attribute__((address_space(3))) void*)(&As[buf][(w * 16 + it * 8) * GBK]),
                16, 0, 0);
            __builtin_amdgcn_global_load_lds(
                (const __attribute__((address_space(1))) void*)(Bb + (long)r * QLORA + k0 + scol),
                (__attribute__((address_space(3))) void*)(&Bs[buf][(w * 16 + it * 8) * GBK]),
                16, 0, 0);
        }
    };

    stage(0, 0);
    asm volatile("s_waitcnt vmcnt(0)" ::: "memory");
    __builtin_amdgcn_s_barrier();

    int cur = 0;
    for (int t = 0; t < nt; ++t) {
        if (t + 1 < nt) stage(cur ^ 1, (t + 1) * GBK);

        const uint aa  = a_base + (uint)(cur * (GBM * GBK * 2));
        const uint bb  = b_base + (uint)(cur * (GBN * GBK * 2));
        const uint aaX = aa ^ 64u;
        const uint bbX = bb ^ 64u;
        bf16x8 a00, a01, a02, a03, a10, a11, a12, a13, b00, b01, b10, b11;
        asm volatile("ds_read_b128 %0, %1 offset:0"    : "=v"(a00) : "v"(aa));
        asm volatile("ds_read_b128 %0, %1 offset:2048" : "=v"(a01) : "v"(aa));
        asm volatile("ds_read_b128 %0, %1 offset:4096" : "=v"(a02) : "v"(aa));
        asm volatile("ds_read_b128 %0, %1 offset:6144" : "=v"(a03) : "v"(aa));
        asm volatile("ds_read_b128 %0, %1 offset:0"    : "=v"(a10) : "v"(aaX));
        asm volatile("ds_read_b128 %0, %1 offset:2048" : "=v"(a11) : "v"(aaX));
        asm volatile("ds_read_b128 %0, %1 offset:4096" : "=v"(a12) : "v"(aaX));
        asm volatile("ds_read_b128 %0, %1 offset:6144" : "=v"(a13) : "v"(aaX));
        asm volatile("ds_read_b128 %0, %1 offset:0"    : "=v"(b00) : "v"(bb));
        asm volatile("ds_read_b128 %0, %1 offset:2048" : "=v"(b01) : "v"(bb));
        asm volatile("ds_read_b128 %0, %1 offset:0"    : "=v"(b10) : "v"(bbX));
        asm volatile("ds_read_b128 %0, %1 offset:2048" : "=v"(b11) : "v"(bbX));
        asm volatile("s_waitcnt lgkmcnt(0)" ::: "memory");
        __builtin_amdgcn_sched_barrier(0);

        acc[0][0] = __builtin_amdgcn_mfma_f32_16x16x32_bf16(a00, b00, acc[0][0], 0, 0, 0);
        acc[0][1] = __builtin_amdgcn_mfma_f32_16x16x32_bf16(a00, b01, acc[0][1], 0, 0, 0);
        acc[1][0] = __builtin_amdgcn_mfma_f32_16x16x32_bf16(a01, b00, acc[1][0], 0, 0, 0);
        acc[1][1] = __builtin_amdgcn_mfma_f32_16x16x32_bf16(a01, b01, acc[1][1], 0, 0, 0);
        acc[2][0] = __builtin_amdgcn_mfma_f32_16x16x32_bf16(a02, b00, acc[2][0], 0, 0, 0);
        acc[2][1] = __builtin_amdgcn_mfma_f32_16x16x32_bf16(a02, b01, acc[2][1], 0, 0, 0);
        acc[3][0] = __builtin_amdgcn_mfma_f32_16x16x32_bf16(a03, b00, acc[3][0], 0, 0, 0);
        acc[3][1] = __builtin_amdgcn_mfma_f32_16x16x32_bf16(a03, b01, acc[3][1], 0, 0, 0);
        acc[0][0] = __builtin_amdgcn_mfma_f32_16x16x32_bf16(a10, b10, acc[0][0], 0, 0, 0);
        acc[0][1] = __builtin_amdgcn_mfma_f32_16x16x32_bf16(a10, b11, acc[0][1], 0, 0, 0);
        acc[1][0] = __builtin_amdgcn_mfma_f32_16x16x32_bf16(a11, b10, acc[1][0], 0, 0, 0);
        acc[1][1] = __builtin_amdgcn_mfma_f32_16x16x32_bf16(a11, b11, acc[1][1], 0, 0, 0);
        acc[2][0] = __builtin_amdgcn_mfma_f32_16x16x32_bf16(a12, b10, acc[2][0], 0, 0, 0);
        acc[2][1] = __builtin_amdgcn_mfma_f32_16x16x32_bf16(a12, b11, acc[2][1], 0, 0, 0);
        acc[3][0] = __builtin_amdgcn_mfma_f32_16x16x32_bf16(a13, b10, acc[3][0], 0, 0, 0);
        acc[3][1] = __builtin_amdgcn_mfma_f32_16x16x32_bf16(a13, b11, acc[3][1], 0, 0, 0);

        asm volatile("s_waitcnt vmcnt(0)" ::: "memory");
        __builtin_amdgcn_s_barrier();
        cur ^= 1;
    }

    // fused split_q epilogue
    #pragma unroll
    for (int i = 0; i < 4; i++) {
        #pragma unroll
        for (int j = 0; j < 2; j++) {
            const int row0 = wr * 64 + i * 16 + kg * 4;
            const int col  = bcol + wc * 32 + j * 16 + fr;
            const int h  = col / 192;
            const int jj = col - h * 192;
            if (jj < 128) {
                #pragma unroll
                for (int r = 0; r < 4; r++) {
                    const int t = brow + row0 + r;
                    q_nope[((long)h * T_TOK + t) * NOPE_D + jj] = (bf16_t)acc[i][j][r];
                }
            } else {
                const int idx = jj - 128;
                const int j2 = idx >> 1;
                const int odd = idx & 1;
                #pragma unroll
                for (int r = 0; r < 4; r++) {
                    const int t = brow + row0 + r;
                    const float v = acc[i][j][r];
                    const float p = __shfl_xor(v, 1, 64);
                    const int pos = positions[t];
                    const float c = cos_sin[pos * 64 + j2];
                    const float s = cos_sin[pos * 64 + 32 + j2];
                    const float o = odd ? (v * c + p * s) : (v * c - p * s);
                    q_out[(long)t * 9216 + h * 576 + 512 + (odd ? 32 : 0) + j2] = o;
                }
            }
        }
    }
}

// ---------------- GEMM3: single-shot K=128 kernel ---------------------------
// q_out[:, h, :512] = q_nope[h] @ w_kc[h]. Stage ALL of K (two 64-halves, r8's
// exact layout/swizzle per half) into 64 KB LDS at once -> ONE vmcnt(0)+barrier
// total (vs 3 drains in the looped kernel), then 2 x (12 ds_read + 16 MFMA).
__global__ __launch_bounds__(512) void gemm3_k128(
    const bf16_t* __restrict__ A,   // q_nope, lda=128, head stride T*128
    const bf16_t* __restrict__ Bt,  // wkcT, ldb=2048, head stride 128
    float* __restrict__ C)          // q_out, ldc=9216, head stride 576
{
    __shared__ bf16_t As[2][GBM * GBK];   // per K-half, r8 layout
    __shared__ bf16_t Bs[2][GBN * GBK];

    const int nwg = gridDim.x * gridDim.y;
    const int bid = blockIdx.y * gridDim.x + blockIdx.x;
    const int cpx = nwg >> 3;
    const int swz = (bid & 7) * cpx + (bid >> 3);
    const int bx = swz % gridDim.x;
    const int by = swz / gridDim.x;

    const int tid = threadIdx.x;
    const int lane = tid & 63;
    const int w = tid >> 6;
    const int wr = w >> 2, wc = w & 3;   // wave tile 64x32
    const int fr = lane & 15;
    const int kg = lane >> 4;

    const long brow = (long)by * GBM;
    const long bcol = (long)bx * GBN;

    const bf16_t* Ab = A + (long)blockIdx.z * T_TOK * NOPE_D + brow * NOPE_D;
    const bf16_t* Bb = Bt + blockIdx.z * 128;
    float* Cb = C + blockIdx.z * 576 + brow * 9216;

    const int srow = w * 16 + (lane >> 3);
    const int scol = (((lane & 7) ^ (lane >> 3)) * 8);

    const uint rd_sw = (uint)((kg * 16) ^ ((fr & 7) << 4));

    // stage both K-halves of A and B (8 gload_lds per thread), one drain
    #pragma unroll
    for (int kh = 0; kh < 2; kh++) {
        #pragma unroll
        for (int it = 0; it < 2; it++) {
            const int r = srow + it * 8;
            __builtin_amdgcn_global_load_lds(
                (const __attribute__((address_space(1))) void*)(Ab + (long)r * NOPE_D + kh * 64 + scol),
                (__attribute__((address_space(3))) void*)(&As[kh][(w * 16 + it * 8) * GBK]),
                16, 0, 0);
        }
        #pragma unroll
        for (int it = 0; it < 2; it++) {
            const int r = srow + it * 8;
            __builtin_amdgcn_global_load_lds(
                (const __attribute__((address_space(1))) void*)(Bb + (bcol + r) * 2048 + kh * 64 + scol),
                (__attribute__((address_space(3))) void*)(&Bs[kh][(w * 16 + it * 8) * GBK]),
                16, 0, 0);
        }
    }
    asm volatile("s_waitcnt vmcnt(0)" ::: "memory");
    __builtin_amdgcn_s_barrier();

    f32x4 acc[4][2] = {};

    #pragma unroll
    for (int kh = 0; kh < 2; kh++) {
        const uint aa  = (uint)(uintptr_t)(&As[kh][0]) + (uint)((wr * 64 + fr) * 128) + rd_sw;
        const uint bb  = (uint)(uintptr_t)(&Bs[kh][0]) + (uint)((wc * 32 + fr) * 128) + rd_sw;
        const uint aaX = aa ^ 64u;
        const uint bbX = bb ^ 64u;
        bf16x8 a00, a01, a02, a03, a10, a11, a12, a13, b00, b01, b10, b11;
        asm volatile("ds_read_b128 %0, %1 offset:0"    : "=v"(a00) : "v"(aa));
        asm volatile("ds_read_b128 %0, %1 offset:2048" : "=v"(a01) : "v"(aa));
        asm volatile("ds_read_b128 %0, %1 offset:4096" : "=v"(a02) : "v"(aa));
        asm volatile("ds_read_b128 %0, %1 offset:6144" : "=v"(a03) : "v"(aa));
        asm volatile("ds_read_b128 %0, %1 offset:0"    : "=v"(a10) : "v"(aaX));
        asm volatile("ds_read_b128 %0, %1 offset:2048" : "=v"(a11) : "v"(aaX));
        asm volatile("ds_read_b128 %0, %1 offset:4096" : "=v"(a12) : "v"(aaX));
        asm volatile("ds_read_b128 %0, %1 offset:6144" : "=v"(a13) : "v"(aaX));
        asm volatile("ds_read_b128 %0, %1 offset:0"    : "=v"(b00) : "v"(bb));
        asm volatile("ds_read_b128 %0, %1 offset:2048" : "=v"(b01) : "v"(bb));
        asm volatile("ds_read_b128 %0, %1 offset:0"    : "=v"(b10) : "v"(bbX));
        asm volatile("ds_read_b128 %0, %1 offset:2048" : "=v"(b11) : "v"(bbX));
        asm volatile("s_waitcnt lgkmcnt(0)" ::: "memory");
        __builtin_amdgcn_sched_barrier(0);

        acc[0][0] = __builtin_amdgcn_mfma_f32_16x16x32_bf16(a00, b00, acc[0][0], 0, 0, 0);
        acc[0][1] = __builtin_amdgcn_mfma_f32_16x16x32_bf16(a00, b01, acc[0][1], 0, 0, 0);
        acc[1][0] = __builtin_amdgcn_mfma_f32_16x16x32_bf16(a01, b00, acc[1][0], 0, 0, 0);
        acc[1][1] = __builtin_amdgcn_mfma_f32_16x16x32_bf16(a01, b01, acc[1][1], 0, 0, 0);
        acc[2][0] = __builtin_amdgcn_mfma_f32_16x16x32_bf16(a02, b00, acc[2][0], 0, 0, 0);
        acc[2][1] = __builtin_amdgcn_mfma_f32_16x16x32_bf16(a02, b01, acc[2][1], 0, 0, 0);
        acc[3][0] = __builtin_amdgcn_mfma_f32_16x16x32_bf16(a03, b00, acc[3][0], 0, 0, 0);
        acc[3][1] = __builtin_amdgcn_mfma_f32_16x16x32_bf16(a03, b01, acc[3][1], 0, 0, 0);
        acc[0][0] = __builtin_amdgcn_mfma_f32_16x16x32_bf16(a10, b10, acc[0][0], 0, 0, 0);
        acc[0][1] = __builtin_amdgcn_mfma_f32_16x16x32_bf16(a10, b11, acc[0][1], 0, 0, 0);
        acc[1][0] = __builtin_amdgcn_mfma_f32_16x16x32_bf16(a11, b10, acc[1][0], 0, 0, 0);
        acc[1][1] = __builtin_amdgcn_mfma_f32_16x16x32_bf16(a11, b11, acc[1][1], 0, 0, 0);
        acc[2][0] = __builtin_amdgcn_mfma_f32_16x16x32_bf16(a12, b10, acc[2][0], 0, 0, 0);
        acc[2][1] = __builtin_amdgcn_mfma_f32_16x16x32_bf16(a12, b11, acc[2][1], 0, 0, 0);
        acc[3][0] = __builtin_amdgcn_mfma_f32_16x16x32_bf16(a13, b10, acc[3][0], 0, 0, 0);
        acc[3][1] = __builtin_amdgcn_mfma_f32_16x16x32_bf16(a13, b11, acc[3][1], 0, 0, 0);
    }

    #pragma unroll
    for (int i = 0; i < 4; i++) {
        #pragma unroll
        for (int j = 0; j < 2; j++) {
            const int row0 = wr * 64 + i * 16 + kg * 4;
            const long col = bcol + wc * 32 + j * 16 + fr;
            #pragma unroll
            for (int r = 0; r < 4; r++)
                Cb[(long)(row0 + r) * 9216 + col] = acc[i][j][r];
        }
    }
}

// ---------------- launcher ----------------

extern "C" void kernel_launch(void* const* d_in, const int* in_sizes, int n_in,
                              void* d_out, int out_size, void* d_ws, size_t ws_size,
                              hipStream_t stream)
{
    const float* hs       = (const float*)d_in[0];
    const int*   positions= (const int*)d_in[1];
    const float* w_qkv_a  = (const float*)d_in[2];
    const float* q_a_ln_w = (const float*)d_in[3];
    const float* w_q_b    = (const float*)d_in[4];
    const float* kv_a_ln_w= (const float*)d_in[5];
    const float* w_kc     = (const float*)d_in[6];
    const float* cos_sin  = (const float*)d_in[7];
    const float* k_cache_in  = (const float*)d_in[8];
    const float* rope_cache_in = (const float*)d_in[9];
    const int*   slot_map = (const int*)d_in[10];

    float* out   = (float*)d_out;
    float* q_out = out;                       // 4096*16*576
    float* k_out = out + 37748736;            // 4096*576
    float* kc_out = out + 40108032;           // 16384*512
    float* rc_out = out + 48496640;           // 16384*64

    char* ws = (char*)d_ws;
    // common region (live during GEMM1)
    bf16_t* hs_bf  = (bf16_t*)(ws + 0);            // 58,720,256 B
    bf16_t* wqkvaT = (bf16_t*)(ws + 58720256);     // 30,277,632 B
    bf16_t* wqbT   = (bf16_t*)(ws + 88997888);     //  9,437,184 B
    bf16_t* wkcT   = (bf16_t*)(ws + 98435072);     //  2,097,152 B
    float*  qkv0   = (float*)(ws + 100532224);     // 34,603,008 B

    const bool splitk = ws_size >= (size_t)169738240;

    float*  qkv1;
    bf16_t* q_a;
    bf16_t* q_nope;
    if (splitk) {
        qkv1   = (float*)(ws + 135135232);         // 34,603,008 B (dead after rmsq_kside)
        q_a    = (bf16_t*)(ws + 0);                // hs_bf region, dead after GEMM1
        q_nope = (bf16_t*)(ws + 135135232);        // reuse qkv1 slot after rmsq_kside
    } else {
        qkv1   = nullptr;
        q_a    = (bf16_t*)(ws + 135135232);
        q_nope = (bf16_t*)(ws + 100532224);        // reuse qkv0 slot
    }

    // caches: full copy, then scatter-overwrite in rmsq_kside
    hipMemcpyAsync(kc_out, k_cache_in, (size_t)16384 * 512 * 4, hipMemcpyDeviceToDevice, stream);
    hipMemcpyAsync(rc_out, rope_cache_in, (size_t)16384 * 64 * 4, hipMemcpyDeviceToDevice, stream);

    cast_f32_bf16<<<2048, 256, 0, stream>>>(hs, hs_bf, (long)T_TOK * H_DIM / 8);
    transpose_cast<<<dim3(NQKV / 32, H_DIM / 32), 256, 0, stream>>>(w_qkv_a, wqkvaT, H_DIM, NQKV);
    transpose_cast<<<dim3(NQB / 32, QLORA / 32), 256, 0, stream>>>(w_q_b, wqbT, QLORA, NQB);
    transpose_cast<<<dim3(512 / 32, 2048 / 32), 256, 0, stream>>>(w_kc, wkcT, 2048, 512);

    // GEMM1: qkv = hs @ w_qkv_a   (4096 x 2112, K=7168)
    if (splitk) {
        gemm_mfma<<<dim3((NQKV + GBN - 1) / GBN, T_TOK / GBM, 2), 512, 0, stream>>>(
            hs_bf, H_DIM, 3584, wqkvaT, H_DIM, 3584,
            qkv0, NQKV, (long)T_TOK * NQKV, 3584, NQKV);
    } else {
        gemm_mfma<<<dim3((NQKV + GBN - 1) / GBN, T_TOK / GBM, 1), 512, 0, stream>>>(
            hs_bf, H_DIM, 0, wqkvaT, H_DIM, 0, qkv0, NQKV, 0, H_DIM, NQKV);
    }

    rmsq_kside_kernel<<<T_TOK, 256, 0, stream>>>(qkv0, qkv1, q_a_ln_w, kv_a_ln_w,
                                                 cos_sin, positions, slot_map,
                                                 q_a, k_out, kc_out, rc_out);

    // GEMM2 + fused split_q: writes q_nope (bf16) and q_out[..., 512:576]
    gemm2_fused<<<dim3(NQB / GBN, T_TOK / GBM), 512, 0, stream>>>(
        q_a, wqbT, cos_sin, positions, q_nope, q_out);

    // GEMM3 (batched over heads): single-shot K=128
    gemm3_k128<<<dim3(KVLORA / GBN, T_TOK / GBM, NHEAD), 512, 0, stream>>>(
        q_nope, wkcT, q_out);
}